// Round 1
// baseline (54.915 us; speedup 1.0000x reference)
//
#include <hip/hip_runtime.h>

#define HW_ 25600            // 160*160
#define CHW_ (32 * 25600)    // C*H*W
#define NPIX 819200          // 32*160*160

// Fold the "mean of top-4" stat into the top-4 weights:
// w1e[o][g*4+i] = w1[o][g*5+i] + 0.25*w1[o][g*5+4]   (o in 0..63, g in 0..3, i in 0..3)
__global__ void dgqp_prep_w1(const float* __restrict__ w1, float* __restrict__ w1e) {
    int t = blockIdx.x * blockDim.x + threadIdx.x;
    if (t < 1024) {
        int o = t >> 4, cc = t & 15, g = cc >> 2, i = cc & 3;
        w1e[t] = w1[o * 20 + g * 5 + i] + 0.25f * w1[o * 20 + g * 5 + 4];
    }
}

__global__ __launch_bounds__(256) void dgqp_main(
    const float* __restrict__ x,
    const float* __restrict__ w1e,   // [64][16]
    const float* __restrict__ b1,    // [64]
    const float* __restrict__ w2,    // [64]
    const float* __restrict__ b2,    // [1]
    float* __restrict__ out)         // [819200]
{
    const int idx = blockIdx.x * 256 + threadIdx.x;      // < NPIX exactly
    const int n = idx / HW_;                             // uniform per block (25600 % 256 == 0)
    const int rem = idx - n * HW_;
    const float* xb = x + (size_t)n * CHW_ + rem;

    float s[16];
    #pragma unroll
    for (int g = 0; g < 4; ++g) {
        float v[8];
        #pragma unroll
        for (int b = 0; b < 8; ++b) v[b] = xb[(g * 8 + b) * HW_];
        float m = v[0];
        #pragma unroll
        for (int b = 1; b < 8; ++b) m = fmaxf(m, v[b]);
        // softmax numerators; top-4 of exp == top-4 of v (exp monotone)
        float sum = 0.f;
        float t0 = 0.f, t1 = 0.f, t2 = 0.f, t3 = 0.f;  // exps are > 0
        #pragma unroll
        for (int b = 0; b < 8; ++b) {
            float e = __expf(v[b] - m);
            sum += e;
            // branchless insertion into sorted-descending top-4
            float u0 = fminf(t0, e);  t0 = fmaxf(t0, e);
            float u1 = fminf(t1, u0); t1 = fmaxf(t1, u0);
            float u2 = fminf(t2, u1); t2 = fmaxf(t2, u1);
            t3 = fmaxf(t3, u2);
        }
        float inv = __builtin_amdgcn_rcpf(sum);
        s[g * 4 + 0] = t0 * inv;
        s[g * 4 + 1] = t1 * inv;
        s[g * 4 + 2] = t2 * inv;
        s[g * 4 + 3] = t3 * inv;
    }

    // layer 1 (20->64 folded to 16->64) + ReLU, fused with layer 2 (64->1)
    float z = b2[0];
    #pragma unroll
    for (int o = 0; o < 64; ++o) {
        float acc = b1[o];
        #pragma unroll
        for (int c = 0; c < 16; ++c) acc = fmaf(s[c], w1e[o * 16 + c], acc);
        z = fmaf(w2[o], fmaxf(acc, 0.f), z);
    }
    out[idx] = 1.f / (1.f + __expf(-z));
}

extern "C" void kernel_launch(void* const* d_in, const int* in_sizes, int n_in,
                              void* d_out, int out_size, void* d_ws, size_t ws_size,
                              hipStream_t stream) {
    const float* x  = (const float*)d_in[0];
    const float* w1 = (const float*)d_in[1];
    const float* b1 = (const float*)d_in[2];
    const float* w2 = (const float*)d_in[3];
    const float* b2 = (const float*)d_in[4];
    float* out = (float*)d_out;
    float* w1e = (float*)d_ws;   // 1024 floats = 4 KB scratch

    dgqp_prep_w1<<<4, 256, 0, stream>>>(w1, w1e);
    dgqp_main<<<NPIX / 256, 256, 0, stream>>>(x, w1e, b1, w2, b2, out);
}